// Round 2
// baseline (2426.034 us; speedup 1.0000x reference)
//
#include <hip/hip_runtime.h>
#include <hip/hip_bf16.h>

#define BB 4
#define CC 256
#define HW 4096
#define DD 128
#define CIN 768

static __device__ __forceinline__ void ld4(float* dst, const float* src) {
  float4 t = *(const float4*)src;
  dst[0] = t.x; dst[1] = t.y; dst[2] = t.z; dst[3] = t.w;
}

// ---------------- K1: q/k/v 1x1 conv. GEMM (128x256)@(256x4096) per (which,b)
__global__ __launch_bounds__(256) void k_qkv(
    const float* __restrict__ src, const float* __restrict__ tgt,
    const float* __restrict__ Wq, const float* __restrict__ bq,
    const float* __restrict__ Wk, const float* __restrict__ bk,
    const float* __restrict__ Wv, const float* __restrict__ bv,
    float* __restrict__ qw, float* __restrict__ kwp, float* __restrict__ vwp)
{
  __shared__ float Wt[32][132];   // [c][r], transposed weight chunk
  __shared__ float Xs[32][68];    // [c][p]
  const int tid = threadIdx.x;
  const int tx = tid & 15, ty = tid >> 4;
  const int p0 = blockIdx.x * 64;
  const int which = blockIdx.y;
  const int b = blockIdx.z;
  const float* X    = (which == 0) ? src : tgt;
  const float* Wm   = (which == 0) ? Wq : (which == 1) ? Wk : Wv;
  const float* bias = (which == 0) ? bq : (which == 1) ? bk : bv;
  float* out        = (which == 0) ? qw : (which == 1) ? kwp : vwp;

  float acc[8][4];
#pragma unroll
  for (int i = 0; i < 8; ++i)
#pragma unroll
    for (int j = 0; j < 4; ++j) acc[i][j] = 0.f;

  for (int kk = 0; kk < CC; kk += 32) {
    __syncthreads();
#pragma unroll
    for (int u = 0; u < 4; ++u) {              // 1024 float4 groups: Wt
      int e = tid + 256 * u;
      int c4 = (e & 7) * 4, r = e >> 3;        // r 0..127
      float w[4]; ld4(w, &Wm[r * CC + kk + c4]);
      Wt[c4 + 0][r] = w[0]; Wt[c4 + 1][r] = w[1];
      Wt[c4 + 2][r] = w[2]; Wt[c4 + 3][r] = w[3];
    }
#pragma unroll
    for (int u = 0; u < 2; ++u) {              // 512 float4 groups: Xs
      int e = tid + 256 * u;
      int p4 = (e & 15) * 4, c = e >> 4;       // c 0..31
      *(float4*)&Xs[c][p4] = *(const float4*)&X[(b * CC + kk + c) * HW + p0 + p4];
    }
    __syncthreads();
#pragma unroll 4
    for (int c = 0; c < 32; ++c) {
      float wa[8], xb[4];
      ld4(wa, &Wt[c][ty * 8]); ld4(wa + 4, &Wt[c][ty * 8 + 4]);
      ld4(xb, &Xs[c][tx * 4]);
#pragma unroll
      for (int rr = 0; rr < 8; ++rr)
#pragma unroll
        for (int pp = 0; pp < 4; ++pp) acc[rr][pp] += wa[rr] * xb[pp];
    }
  }
#pragma unroll
  for (int rr = 0; rr < 8; ++rr) {
    int r = ty * 8 + rr;
    float bv_ = bias[r];
    float4 o4 = make_float4(acc[rr][0] + bv_, acc[rr][1] + bv_,
                            acc[rr][2] + bv_, acc[rr][3] + bv_);
    *(float4*)&out[(b * DD + r) * HW + p0 + tx * 4] = o4;
  }
}

// ---------------- K2: l_j = sum_i exp(s[i,j]); store reciprocal
__global__ __launch_bounds__(256) void k_lsum(
    const float* __restrict__ qw, const float* __restrict__ kwp,
    float* __restrict__ rl)
{
  __shared__ float Qs[128][68];   // q[c][j] for this j-tile (persists)
  __shared__ float Kh[64][68];    // k[c][i] half-channel chunk
  __shared__ float Ps[16][68];
  const int tid = threadIdx.x;
  const int tx = tid & 15, ty = tid >> 4;
  const int j0 = blockIdx.x * 64;
  const int b = blockIdx.y;

#pragma unroll
  for (int u = 0; u < 8; ++u) {                // 2048 float4
    int e = tid + 256 * u;
    int j4 = (e & 15) * 4, c = e >> 4;         // c 0..127
    *(float4*)&Qs[c][j4] = *(const float4*)&qw[(b * DD + c) * HW + j0 + j4];
  }

  float racc[4] = {0.f, 0.f, 0.f, 0.f};

  for (int i0 = 0; i0 < HW; i0 += 64) {
    float s[4][4];
#pragma unroll
    for (int a = 0; a < 4; ++a)
#pragma unroll
      for (int jj = 0; jj < 4; ++jj) s[a][jj] = 0.f;

#pragma unroll
    for (int hf = 0; hf < 2; ++hf) {
      __syncthreads();
#pragma unroll
      for (int u = 0; u < 4; ++u) {            // 1024 float4
        int e = tid + 256 * u;
        int i4 = (e & 15) * 4, c = e >> 4;     // c 0..63
        *(float4*)&Kh[c][i4] =
            *(const float4*)&kwp[(b * DD + hf * 64 + c) * HW + i0 + i4];
      }
      __syncthreads();
#pragma unroll 8
      for (int c = 0; c < 64; ++c) {
        float ka[4], qa[4];
        ld4(ka, &Kh[c][ty * 4]);
        ld4(qa, &Qs[hf * 64 + c][tx * 4]);
#pragma unroll
        for (int a = 0; a < 4; ++a)
#pragma unroll
          for (int jj = 0; jj < 4; ++jj) s[a][jj] += ka[a] * qa[jj];
      }
    }
#pragma unroll
    for (int jj = 0; jj < 4; ++jj)
      racc[jj] += __expf(s[0][jj]) + __expf(s[1][jj]) +
                  __expf(s[2][jj]) + __expf(s[3][jj]);
  }
  __syncthreads();
#pragma unroll
  for (int jj = 0; jj < 4; ++jj) Ps[ty][tx * 4 + jj] = racc[jj];
  __syncthreads();
  if (tid < 64) {
    float sum = 0.f;
#pragma unroll
    for (int t = 0; t < 16; ++t) sum += Ps[t][tid];
    rl[b * HW + j0 + tid] = 1.f / sum;
  }
}

// ---------------- K3: out[i,c] = sum_j exp(s_ij)/l_j * v[j,c]; ao layout (B,d,HW)
__global__ __launch_bounds__(256) void k_attnout(
    const float* __restrict__ qw, const float* __restrict__ kwp,
    const float* __restrict__ vwp, const float* __restrict__ rl,
    float* __restrict__ ao)
{
  __shared__ float sA[64][68];  // K half [c][i]  /  V half [j][c]
  __shared__ float sB[64][68];  // Q half [c][j]
  __shared__ float sP[64][68];  // P [j][i]
  __shared__ float rls[64];
  const int tid = threadIdx.x;
  const int tx = tid & 15, ty = tid >> 4;
  const int i0 = blockIdx.x * 64;
  const int b = blockIdx.y;

  float acc[4][8];
#pragma unroll
  for (int i = 0; i < 4; ++i)
#pragma unroll
    for (int j = 0; j < 8; ++j) acc[i][j] = 0.f;

  for (int j0 = 0; j0 < HW; j0 += 64) {
    float s[4][4];
#pragma unroll
    for (int a = 0; a < 4; ++a)
#pragma unroll
      for (int jj = 0; jj < 4; ++jj) s[a][jj] = 0.f;

#pragma unroll
    for (int hf = 0; hf < 2; ++hf) {
      __syncthreads();
#pragma unroll
      for (int u = 0; u < 4; ++u) {
        int e = tid + 256 * u;
        int x4 = (e & 15) * 4, c = e >> 4;     // c 0..63
        *(float4*)&sA[c][x4] =
            *(const float4*)&kwp[(b * DD + hf * 64 + c) * HW + i0 + x4];
        *(float4*)&sB[c][x4] =
            *(const float4*)&qw[(b * DD + hf * 64 + c) * HW + j0 + x4];
      }
      if (hf == 0 && tid < 64) rls[tid] = rl[b * HW + j0 + tid];
      __syncthreads();
#pragma unroll 8
      for (int c = 0; c < 64; ++c) {
        float ka[4], qa[4];
        ld4(ka, &sA[c][ty * 4]);
        ld4(qa, &sB[c][tx * 4]);
#pragma unroll
        for (int a = 0; a < 4; ++a)
#pragma unroll
          for (int jj = 0; jj < 4; ++jj) s[a][jj] += ka[a] * qa[jj];
      }
    }
    // P = exp(s) * (1/l_j), transposed into LDS: sP[j][i]
#pragma unroll
    for (int jj = 0; jj < 4; ++jj) {
      float r = rls[tx * 4 + jj];
#pragma unroll
      for (int a = 0; a < 4; ++a)
        sP[tx * 4 + jj][ty * 4 + a] = __expf(s[a][jj]) * r;
    }
#pragma unroll
    for (int hf = 0; hf < 2; ++hf) {
      __syncthreads();                          // all sP written / sA free
#pragma unroll
      for (int u = 0; u < 4; ++u) {
        int e = tid + 256 * u;
        int j4 = (e & 15) * 4, c = e >> 4;      // c 0..63
        float v4[4];
        ld4(v4, &vwp[(b * DD + hf * 64 + c) * HW + j0 + j4]);
        sA[j4 + 0][c] = v4[0]; sA[j4 + 1][c] = v4[1];
        sA[j4 + 2][c] = v4[2]; sA[j4 + 3][c] = v4[3];
      }
      __syncthreads();
#pragma unroll 8
      for (int j = 0; j < 64; ++j) {
        float pa[4], va[4];
        ld4(pa, &sP[j][tx * 4]);
        ld4(va, &sA[j][ty * 4]);
#pragma unroll
        for (int ii = 0; ii < 4; ++ii)
#pragma unroll
          for (int c4 = 0; c4 < 4; ++c4)
            acc[ii][hf * 4 + c4] += pa[ii] * va[c4];
      }
    }
  }
#pragma unroll
  for (int cc = 0; cc < 8; ++cc) {
    int c = (cc >> 2) * 64 + ty * 4 + (cc & 3);
    float4 o4 = make_float4(acc[0][cc], acc[1][cc], acc[2][cc], acc[3][cc]);
    *(float4*)&ao[(b * DD + c) * HW + i0 + tx * 4] = o4;
  }
}

// ---------------- K4: y = target + gamma * (Wp @ ao + bp)
__global__ __launch_bounds__(256) void k_proj(
    const float* __restrict__ ao, const float* __restrict__ tgt,
    const float* __restrict__ Wp, const float* __restrict__ bp,
    const float* __restrict__ gamma, float* __restrict__ yb)
{
  __shared__ float Wt[32][132];
  __shared__ float Xs[32][68];
  const int tid = threadIdx.x;
  const int tx = tid & 15, ty = tid >> 4;
  const int p0 = blockIdx.x * 64;
  const int ro = blockIdx.y * 128;
  const int b = blockIdx.z;
  const float g0 = gamma[0];

  float acc[8][4];
#pragma unroll
  for (int i = 0; i < 8; ++i)
#pragma unroll
    for (int j = 0; j < 4; ++j) acc[i][j] = 0.f;

  for (int kk = 0; kk < DD; kk += 32) {
    __syncthreads();
#pragma unroll
    for (int u = 0; u < 4; ++u) {
      int e = tid + 256 * u;
      int c4 = (e & 7) * 4, r = e >> 3;        // r 0..127
      float w[4]; ld4(w, &Wp[(ro + r) * DD + kk + c4]);
      Wt[c4 + 0][r] = w[0]; Wt[c4 + 1][r] = w[1];
      Wt[c4 + 2][r] = w[2]; Wt[c4 + 3][r] = w[3];
    }
#pragma unroll
    for (int u = 0; u < 2; ++u) {
      int e = tid + 256 * u;
      int p4 = (e & 15) * 4, c = e >> 4;
      *(float4*)&Xs[c][p4] = *(const float4*)&ao[(b * DD + kk + c) * HW + p0 + p4];
    }
    __syncthreads();
#pragma unroll 4
    for (int c = 0; c < 32; ++c) {
      float wa[8], xb[4];
      ld4(wa, &Wt[c][ty * 8]); ld4(wa + 4, &Wt[c][ty * 8 + 4]);
      ld4(xb, &Xs[c][tx * 4]);
#pragma unroll
      for (int rr = 0; rr < 8; ++rr)
#pragma unroll
        for (int pp = 0; pp < 4; ++pp) acc[rr][pp] += wa[rr] * xb[pp];
    }
  }
#pragma unroll
  for (int rr = 0; rr < 8; ++rr) {
    int r = ro + ty * 8 + rr;
    int idx = (b * CC + r) * HW + p0 + tx * 4;
    float4 t4 = *(const float4*)&tgt[idx];
    float bpv = bp[r];
    float4 o4 = make_float4(t4.x + g0 * (acc[rr][0] + bpv),
                            t4.y + g0 * (acc[rr][1] + bpv),
                            t4.z + g0 * (acc[rr][2] + bpv),
                            t4.w + g0 * (acc[rr][3] + bpv));
    *(float4*)&yb[idx] = o4;
  }
}

// ---------------- K5: 3x3 conv over concat([y, upsample2x(prev)]) -> cbuf
__global__ __launch_bounds__(256) void k_conv(
    const float* __restrict__ yb, const float* __restrict__ prev,
    const float* __restrict__ Wc, const float* __restrict__ bcw,
    float* __restrict__ cbuf)
{
  __shared__ float xs[16][3][68];   // [c][kh][col] col = w+1 (halo)
  __shared__ float wt[144][68];     // [c*9 + kh*3 + kw][o]
  const int tid = threadIdx.x;
  const int tx = tid & 15, ty = tid >> 4;
  const int h = blockIdx.x;
  const int o0 = blockIdx.y * 64;
  const int b = blockIdx.z;

  float acc[4][4];
#pragma unroll
  for (int i = 0; i < 4; ++i)
#pragma unroll
    for (int j = 0; j < 4; ++j) acc[i][j] = 0.f;

  for (int cb0 = 0; cb0 < CIN; cb0 += 16) {
    __syncthreads();
    // stage input rows (3 kh) with zero-padded halo
    for (int e = tid; e < 3168; e += 256) {
      int col = e % 66; int rest = e / 66;
      int r = rest % 3; int c = rest / 3;
      int hr = h + r - 1; int wsrc = col - 1;
      float v = 0.f;
      if (hr >= 0 && hr < 64 && wsrc >= 0 && wsrc < 64) {
        int ci = cb0 + c;
        v = (ci < 256)
              ? yb[(b * CC + ci) * HW + hr * 64 + wsrc]
              : prev[(b * 512 + (ci - 256)) * 1024 + (hr >> 1) * 32 + (wsrc >> 1)];
      }
      xs[c][r][col] = v;
    }
    // stage weights: contiguous 144-float runs per o
    for (int e = tid; e < 2304; e += 256) {
      int q4 = (e % 36) * 4; int ol = e / 36;
      float w[4]; ld4(w, &Wc[(size_t)(o0 + ol) * 6912 + cb0 * 9 + q4]);
      wt[q4 + 0][ol] = w[0]; wt[q4 + 1][ol] = w[1];
      wt[q4 + 2][ol] = w[2]; wt[q4 + 3][ol] = w[3];
    }
    __syncthreads();
#pragma unroll 4
    for (int c = 0; c < 16; ++c) {
#pragma unroll
      for (int kh = 0; kh < 3; ++kh) {
        float xv[6];
#pragma unroll
        for (int u = 0; u < 6; ++u) xv[u] = xs[c][kh][tx * 4 + u];
#pragma unroll
        for (int kw = 0; kw < 3; ++kw) {
          float wa[4];
          ld4(wa, &wt[c * 9 + kh * 3 + kw][ty * 4]);
#pragma unroll
          for (int oo = 0; oo < 4; ++oo)
#pragma unroll
            for (int wwi = 0; wwi < 4; ++wwi)
              acc[oo][wwi] += wa[oo] * xv[wwi + kw];
        }
      }
    }
  }
#pragma unroll
  for (int oo = 0; oo < 4; ++oo) {
    int o = o0 + ty * 4 + oo;
    float bcv = bcw[o];
    float4 o4 = make_float4(acc[oo][0] + bcv, acc[oo][1] + bcv,
                            acc[oo][2] + bcv, acc[oo][3] + bcv);
    *(float4*)&cbuf[(b * CC + o) * HW + h * 64 + tx * 4] = o4;
  }
}

// ---------------- K6: InstanceNorm (biased var, eps=1e-5) + ReLU -> f32 out
__global__ __launch_bounds__(256) void k_inorm(
    const float* __restrict__ cbuf, float* __restrict__ out)
{
  __shared__ float buf[4096];
  __shared__ float red[8];
  const int tid = threadIdx.x;
  const int ch = blockIdx.x;                 // b*256 + c
  const float* srcp = cbuf + (size_t)ch * HW;

  float s = 0.f, sq = 0.f;
#pragma unroll
  for (int u = 0; u < 4; ++u) {
    int idx = u * 1024 + tid * 4;
    float4 v = *(const float4*)&srcp[idx];
    *(float4*)&buf[idx] = v;
    s  += v.x + v.y + v.z + v.w;
    sq += v.x * v.x + v.y * v.y + v.z * v.z + v.w * v.w;
  }
#pragma unroll
  for (int m = 32; m >= 1; m >>= 1) {
    s  += __shfl_xor(s, m, 64);
    sq += __shfl_xor(sq, m, 64);
  }
  if ((tid & 63) == 0) { red[tid >> 6] = s; red[4 + (tid >> 6)] = sq; }
  __syncthreads();
  if (tid == 0) {
    float S = red[0] + red[1] + red[2] + red[3];
    float Q = red[4] + red[5] + red[6] + red[7];
    float mean = S * (1.f / HW);
    float var = Q * (1.f / HW) - mean * mean;
    red[0] = mean;
    red[1] = rsqrtf(var + 1e-5f);
  }
  __syncthreads();
  const float mean = red[0], rs = red[1];
#pragma unroll
  for (int u = 0; u < 4; ++u) {
    int idx = u * 1024 + tid * 4;
    float4 v = *(const float4*)&buf[idx];
    float4 o4 = make_float4(fmaxf((v.x - mean) * rs, 0.f),
                            fmaxf((v.y - mean) * rs, 0.f),
                            fmaxf((v.z - mean) * rs, 0.f),
                            fmaxf((v.w - mean) * rs, 0.f));
    *(float4*)&out[(size_t)ch * HW + idx] = o4;
  }
}

extern "C" void kernel_launch(void* const* d_in, const int* in_sizes, int n_in,
                              void* d_out, int out_size, void* d_ws, size_t ws_size,
                              hipStream_t stream) {
  const float* src  = (const float*)d_in[0];
  const float* tgt  = (const float*)d_in[1];
  const float* prev = (const float*)d_in[2];
  const float* Wq = (const float*)d_in[3];  const float* bq = (const float*)d_in[4];
  const float* Wk = (const float*)d_in[5];  const float* bk = (const float*)d_in[6];
  const float* Wv = (const float*)d_in[7];  const float* bv = (const float*)d_in[8];
  const float* Wp = (const float*)d_in[9];  const float* bp = (const float*)d_in[10];
  const float* gamma = (const float*)d_in[11];
  const float* Wc = (const float*)d_in[12]; const float* bcw = (const float*)d_in[13];

  float* ws = (float*)d_ws;
  float* qw   = ws;                 // 2,097,152 floats (B,d,HW)
  float* kw   = ws + 2097152;       // 2,097,152
  float* vw   = ws + 4194304;       // 2,097,152
  float* rl   = ws + 6291456;       // 16,384 (1/l_j)
  float* ao   = ws + 6307840;       // 2,097,152 (B,d,HW)
  float* yb   = ws;                 // alias q+k (dead after k_attnout): 4,194,304
  float* cbuf = ws + 4194304;       // alias v/rl/ao (dead after k_proj): 4,194,304
  // total footprint: 8,404,992 floats = 33.6 MB

  k_qkv    <<<dim3(64, 3, BB), 256, 0, stream>>>(src, tgt, Wq, bq, Wk, bk, Wv, bv, qw, kw, vw);
  k_lsum   <<<dim3(64, BB),    256, 0, stream>>>(qw, kw, rl);
  k_attnout<<<dim3(64, BB),    256, 0, stream>>>(qw, kw, vw, rl, ao);
  k_proj   <<<dim3(64, 2, BB), 256, 0, stream>>>(ao, tgt, Wp, bp, gamma, yb);
  k_conv   <<<dim3(64, 4, BB), 256, 0, stream>>>(yb, prev, Wc, bcw, cbuf);
  k_inorm  <<<dim3(1024),      256, 0, stream>>>(cbuf, (float*)d_out);
}

// Round 3
// 1445.483 us; speedup vs baseline: 1.6784x; 1.6784x over previous
//
#include <hip/hip_runtime.h>
#include <hip/hip_bf16.h>

#define BB 4
#define CC 256
#define HW 4096
#define DD 128

typedef __attribute__((ext_vector_type(8))) short bf16x8;
typedef __attribute__((ext_vector_type(4))) float f32x4;

static __device__ __forceinline__ void ld4(float* dst, const float* src) {
  float4 t = *(const float4*)src;
  dst[0] = t.x; dst[1] = t.y; dst[2] = t.z; dst[3] = t.w;
}

// float -> bf16 (RNE) raw bits
static __device__ __forceinline__ short f2b(float f) {
  unsigned u = __float_as_uint(f);
  u += 0x7fffu + ((u >> 16) & 1u);
  return (short)(u >> 16);
}

// ---------------- K1: q/k/v 1x1 conv. GEMM (128x256)@(256x4096) per (which,b)
__global__ __launch_bounds__(256) void k_qkv(
    const float* __restrict__ src, const float* __restrict__ tgt,
    const float* __restrict__ Wq, const float* __restrict__ bq,
    const float* __restrict__ Wk, const float* __restrict__ bk,
    const float* __restrict__ Wv, const float* __restrict__ bv,
    float* __restrict__ qw, float* __restrict__ kwp, float* __restrict__ vwp)
{
  __shared__ float Wt[32][132];
  __shared__ float Xs[32][68];
  const int tid = threadIdx.x;
  const int tx = tid & 15, ty = tid >> 4;
  const int p0 = blockIdx.x * 64;
  const int which = blockIdx.y;
  const int b = blockIdx.z;
  const float* X    = (which == 0) ? src : tgt;
  const float* Wm   = (which == 0) ? Wq : (which == 1) ? Wk : Wv;
  const float* bias = (which == 0) ? bq : (which == 1) ? bk : bv;
  float* out        = (which == 0) ? qw : (which == 1) ? kwp : vwp;

  float acc[8][4];
#pragma unroll
  for (int i = 0; i < 8; ++i)
#pragma unroll
    for (int j = 0; j < 4; ++j) acc[i][j] = 0.f;

  for (int kk = 0; kk < CC; kk += 32) {
    __syncthreads();
#pragma unroll
    for (int u = 0; u < 4; ++u) {
      int e = tid + 256 * u;
      int c4 = (e & 7) * 4, r = e >> 3;
      float w[4]; ld4(w, &Wm[r * CC + kk + c4]);
      Wt[c4 + 0][r] = w[0]; Wt[c4 + 1][r] = w[1];
      Wt[c4 + 2][r] = w[2]; Wt[c4 + 3][r] = w[3];
    }
#pragma unroll
    for (int u = 0; u < 2; ++u) {
      int e = tid + 256 * u;
      int p4 = (e & 15) * 4, c = e >> 4;
      *(float4*)&Xs[c][p4] = *(const float4*)&X[(b * CC + kk + c) * HW + p0 + p4];
    }
    __syncthreads();
#pragma unroll 4
    for (int c = 0; c < 32; ++c) {
      float wa[8], xb[4];
      ld4(wa, &Wt[c][ty * 8]); ld4(wa + 4, &Wt[c][ty * 8 + 4]);
      ld4(xb, &Xs[c][tx * 4]);
#pragma unroll
      for (int rr = 0; rr < 8; ++rr)
#pragma unroll
        for (int pp = 0; pp < 4; ++pp) acc[rr][pp] += wa[rr] * xb[pp];
    }
  }
#pragma unroll
  for (int rr = 0; rr < 8; ++rr) {
    int r = ty * 8 + rr;
    float bv_ = bias[r];
    float4 o4 = make_float4(acc[rr][0] + bv_, acc[rr][1] + bv_,
                            acc[rr][2] + bv_, acc[rr][3] + bv_);
    *(float4*)&out[(b * DD + r) * HW + p0 + tx * 4] = o4;
  }
}

// ---------------- K2: l_j = sum_i exp(s[i,j]); store reciprocal
__global__ __launch_bounds__(256) void k_lsum(
    const float* __restrict__ qw, const float* __restrict__ kwp,
    float* __restrict__ rl)
{
  __shared__ float Qs[128][68];
  __shared__ float Kh[64][68];
  __shared__ float Ps[16][68];
  const int tid = threadIdx.x;
  const int tx = tid & 15, ty = tid >> 4;
  const int j0 = blockIdx.x * 64;
  const int b = blockIdx.y;

#pragma unroll
  for (int u = 0; u < 8; ++u) {
    int e = tid + 256 * u;
    int j4 = (e & 15) * 4, c = e >> 4;
    *(float4*)&Qs[c][j4] = *(const float4*)&qw[(b * DD + c) * HW + j0 + j4];
  }

  float racc[4] = {0.f, 0.f, 0.f, 0.f};

  for (int i0 = 0; i0 < HW; i0 += 64) {
    float s[4][4];
#pragma unroll
    for (int a = 0; a < 4; ++a)
#pragma unroll
      for (int jj = 0; jj < 4; ++jj) s[a][jj] = 0.f;

#pragma unroll
    for (int hf = 0; hf < 2; ++hf) {
      __syncthreads();
#pragma unroll
      for (int u = 0; u < 4; ++u) {
        int e = tid + 256 * u;
        int i4 = (e & 15) * 4, c = e >> 4;
        *(float4*)&Kh[c][i4] =
            *(const float4*)&kwp[(b * DD + hf * 64 + c) * HW + i0 + i4];
      }
      __syncthreads();
#pragma unroll 8
      for (int c = 0; c < 64; ++c) {
        float ka[4], qa[4];
        ld4(ka, &Kh[c][ty * 4]);
        ld4(qa, &Qs[hf * 64 + c][tx * 4]);
#pragma unroll
        for (int a = 0; a < 4; ++a)
#pragma unroll
          for (int jj = 0; jj < 4; ++jj) s[a][jj] += ka[a] * qa[jj];
      }
    }
#pragma unroll
    for (int jj = 0; jj < 4; ++jj)
      racc[jj] += __expf(s[0][jj]) + __expf(s[1][jj]) +
                  __expf(s[2][jj]) + __expf(s[3][jj]);
  }
  __syncthreads();
#pragma unroll
  for (int jj = 0; jj < 4; ++jj) Ps[ty][tx * 4 + jj] = racc[jj];
  __syncthreads();
  if (tid < 64) {
    float sum = 0.f;
#pragma unroll
    for (int t = 0; t < 16; ++t) sum += Ps[t][tid];
    rl[b * HW + j0 + tid] = 1.f / sum;
  }
}

// ---------------- K3: out[i,c] = sum_j exp(s_ij)/l_j * v[j,c]; ao layout (B,d,HW)
__global__ __launch_bounds__(256) void k_attnout(
    const float* __restrict__ qw, const float* __restrict__ kwp,
    const float* __restrict__ vwp, const float* __restrict__ rl,
    float* __restrict__ ao)
{
  __shared__ float sA[64][68];
  __shared__ float sB[64][68];
  __shared__ float sP[64][68];
  __shared__ float rls[64];
  const int tid = threadIdx.x;
  const int tx = tid & 15, ty = tid >> 4;
  const int i0 = blockIdx.x * 64;
  const int b = blockIdx.y;

  float acc[4][8];
#pragma unroll
  for (int i = 0; i < 4; ++i)
#pragma unroll
    for (int j = 0; j < 8; ++j) acc[i][j] = 0.f;

  for (int j0 = 0; j0 < HW; j0 += 64) {
    float s[4][4];
#pragma unroll
    for (int a = 0; a < 4; ++a)
#pragma unroll
      for (int jj = 0; jj < 4; ++jj) s[a][jj] = 0.f;

#pragma unroll
    for (int hf = 0; hf < 2; ++hf) {
      __syncthreads();
#pragma unroll
      for (int u = 0; u < 4; ++u) {
        int e = tid + 256 * u;
        int x4 = (e & 15) * 4, c = e >> 4;
        *(float4*)&sA[c][x4] =
            *(const float4*)&kwp[(b * DD + hf * 64 + c) * HW + i0 + x4];
        *(float4*)&sB[c][x4] =
            *(const float4*)&qw[(b * DD + hf * 64 + c) * HW + j0 + x4];
      }
      if (hf == 0 && tid < 64) rls[tid] = rl[b * HW + j0 + tid];
      __syncthreads();
#pragma unroll 8
      for (int c = 0; c < 64; ++c) {
        float ka[4], qa[4];
        ld4(ka, &sA[c][ty * 4]);
        ld4(qa, &sB[c][tx * 4]);
#pragma unroll
        for (int a = 0; a < 4; ++a)
#pragma unroll
          for (int jj = 0; jj < 4; ++jj) s[a][jj] += ka[a] * qa[jj];
      }
    }
#pragma unroll
    for (int jj = 0; jj < 4; ++jj) {
      float r = rls[tx * 4 + jj];
#pragma unroll
      for (int a = 0; a < 4; ++a)
        sP[tx * 4 + jj][ty * 4 + a] = __expf(s[a][jj]) * r;
    }
#pragma unroll
    for (int hf = 0; hf < 2; ++hf) {
      __syncthreads();
#pragma unroll
      for (int u = 0; u < 4; ++u) {
        int e = tid + 256 * u;
        int j4 = (e & 15) * 4, c = e >> 4;
        float v4[4];
        ld4(v4, &vwp[(b * DD + hf * 64 + c) * HW + j0 + j4]);
        sA[j4 + 0][c] = v4[0]; sA[j4 + 1][c] = v4[1];
        sA[j4 + 2][c] = v4[2]; sA[j4 + 3][c] = v4[3];
      }
      __syncthreads();
#pragma unroll 8
      for (int j = 0; j < 64; ++j) {
        float pa[4], va[4];
        ld4(pa, &sP[j][tx * 4]);
        ld4(va, &sA[j][ty * 4]);
#pragma unroll
        for (int ii = 0; ii < 4; ++ii)
#pragma unroll
          for (int c4 = 0; c4 < 4; ++c4)
            acc[ii][hf * 4 + c4] += pa[ii] * va[c4];
      }
    }
  }
#pragma unroll
  for (int cc = 0; cc < 8; ++cc) {
    int c = (cc >> 2) * 64 + ty * 4 + (cc & 3);
    float4 o4 = make_float4(acc[0][cc], acc[1][cc], acc[2][cc], acc[3][cc]);
    *(float4*)&ao[(b * DD + c) * HW + i0 + tx * 4] = o4;
  }
}

// ---------------- K4: y = target + gamma * (Wp @ ao + bp)  (f32 out)
__global__ __launch_bounds__(256) void k_proj(
    const float* __restrict__ ao, const float* __restrict__ tgt,
    const float* __restrict__ Wp, const float* __restrict__ bp,
    const float* __restrict__ gamma, float* __restrict__ yb)
{
  __shared__ float Wt[32][132];
  __shared__ float Xs[32][68];
  const int tid = threadIdx.x;
  const int tx = tid & 15, ty = tid >> 4;
  const int p0 = blockIdx.x * 64;
  const int ro = blockIdx.y * 128;
  const int b = blockIdx.z;
  const float g0 = gamma[0];

  float acc[8][4];
#pragma unroll
  for (int i = 0; i < 8; ++i)
#pragma unroll
    for (int j = 0; j < 4; ++j) acc[i][j] = 0.f;

  for (int kk = 0; kk < DD; kk += 32) {
    __syncthreads();
#pragma unroll
    for (int u = 0; u < 4; ++u) {
      int e = tid + 256 * u;
      int c4 = (e & 7) * 4, r = e >> 3;
      float w[4]; ld4(w, &Wp[(ro + r) * DD + kk + c4]);
      Wt[c4 + 0][r] = w[0]; Wt[c4 + 1][r] = w[1];
      Wt[c4 + 2][r] = w[2]; Wt[c4 + 3][r] = w[3];
    }
#pragma unroll
    for (int u = 0; u < 2; ++u) {
      int e = tid + 256 * u;
      int p4 = (e & 15) * 4, c = e >> 4;
      *(float4*)&Xs[c][p4] = *(const float4*)&ao[(b * DD + kk + c) * HW + p0 + p4];
    }
    __syncthreads();
#pragma unroll 4
    for (int c = 0; c < 32; ++c) {
      float wa[8], xb[4];
      ld4(wa, &Wt[c][ty * 8]); ld4(wa + 4, &Wt[c][ty * 8 + 4]);
      ld4(xb, &Xs[c][tx * 4]);
#pragma unroll
      for (int rr = 0; rr < 8; ++rr)
#pragma unroll
        for (int pp = 0; pp < 4; ++pp) acc[rr][pp] += wa[rr] * xb[pp];
    }
  }
#pragma unroll
  for (int rr = 0; rr < 8; ++rr) {
    int r = ro + ty * 8 + rr;
    int idx = (b * CC + r) * HW + p0 + tx * 4;
    float4 t4 = *(const float4*)&tgt[idx];
    float bpv = bp[r];
    float4 o4 = make_float4(t4.x + g0 * (acc[rr][0] + bpv),
                            t4.y + g0 * (acc[rr][1] + bpv),
                            t4.z + g0 * (acc[rr][2] + bpv),
                            t4.w + g0 * (acc[rr][3] + bpv));
    *(float4*)&yb[idx] = o4;
  }
}

// ---------------- K4b: pack conv input to NHWC bf16: Xn(B,64,64,768)
// channels 0..255 from yb (f32, NCHW); 256..767 from upsample2x(prev)
__global__ __launch_bounds__(256) void k_pack(
    const float* __restrict__ yb, const float* __restrict__ prev,
    short* __restrict__ Xn)
{
  __shared__ float tile[64][65];
  const int tid = threadIdx.x;
  const int h = blockIdx.x;
  const int ci0 = blockIdx.y * 64;
  const int b = blockIdx.z;

  {
    int w = tid & 63, r = tid >> 6;
    for (int cs = r; cs < 64; cs += 4) {
      int ci = ci0 + cs;
      float v;
      if (ci < 256)
        v = yb[((size_t)b * CC + ci) * HW + h * 64 + w];
      else
        v = prev[((size_t)b * 512 + (ci - 256)) * 1024 + (h >> 1) * 32 + (w >> 1)];
      tile[cs][w] = v;
    }
  }
  __syncthreads();
  {
    int ci = tid & 63, wq = tid >> 6;
    for (int ws2 = wq; ws2 < 64; ws2 += 4) {
      Xn[(((size_t)b * 64 + h) * 64 + ws2) * 768 + ci0 + ci] = f2b(tile[ci][ws2]);
    }
  }
}

// ---------------- K4c: weight repack Wc(256,768,3,3) f32 -> Wb(256,9,768) bf16
__global__ __launch_bounds__(256) void k_wb(
    const float* __restrict__ Wc, short* __restrict__ Wb)
{
  int i = blockIdx.x * 256 + threadIdx.x;      // 0 .. 1,769,471
  int o = i / 6912;
  int rem = i - o * 6912;
  int khw = rem / 768;
  int ci = rem - khw * 768;
  Wb[i] = f2b(Wc[(size_t)o * 6912 + ci * 9 + khw]);
}

// ---------------- K5: 3x3 conv, implicit GEMM, bf16 MFMA -> cb (bf16)
// WG: 128 Cout x 64 pixels (one h row). 4 waves; wave -> 32 Cout.
// grid (64 h, 2 m-half, 4 b) = 512 WGs.
__global__ __launch_bounds__(256) void k_conv_mfma(
    const short* __restrict__ Xn,   // (B,64,64,768) bf16
    const short* __restrict__ Wb,   // (256,9,768) bf16
    const float* __restrict__ bcw,
    short* __restrict__ cb)         // (B,256,4096) bf16
{
  const int tid = threadIdx.x;
  const int wv = tid >> 6;
  const int lane = tid & 63;
  const int t = lane & 15, q = lane >> 4;
  const int h = blockIdx.x;
  const int m0 = blockIdx.y * 128 + wv * 32;
  const int b = blockIdx.z;

  const f32x4 zf = {0.f, 0.f, 0.f, 0.f};
  const bf16x8 zb = {0, 0, 0, 0, 0, 0, 0, 0};
  f32x4 acc[2][4];
#pragma unroll
  for (int mt = 0; mt < 2; ++mt)
#pragma unroll
    for (int nt = 0; nt < 4; ++nt) acc[mt][nt] = zf;

  for (int ci0 = 0; ci0 < 768; ci0 += 32) {
    for (int kh = 0; kh < 3; ++kh) {
      const int hr = h + kh - 1;
      const bool vh = ((unsigned)hr < 64u);
      const short* xrow = Xn + (((size_t)b * 64 + hr) * 64) * 768 + ci0 + q * 8;
      const short* wrow = Wb + (size_t)(m0 + t) * 6912 + kh * 3 * 768 + ci0 + q * 8;
#pragma unroll
      for (int kw = 0; kw < 3; ++kw) {
        bf16x8 bf[4];
#pragma unroll
        for (int nt = 0; nt < 4; ++nt) {
          int col = nt * 16 + t + kw - 1;
          bf[nt] = (vh && (unsigned)col < 64u)
                       ? *(const bf16x8*)(xrow + (ptrdiff_t)col * 768)
                       : zb;
        }
        bf16x8 af[2];
        af[0] = *(const bf16x8*)(wrow + kw * 768);
        af[1] = *(const bf16x8*)(wrow + 16 * 6912 + kw * 768);
#pragma unroll
        for (int mt = 0; mt < 2; ++mt)
#pragma unroll
          for (int nt = 0; nt < 4; ++nt)
            acc[mt][nt] = __builtin_amdgcn_mfma_f32_16x16x32_bf16(
                af[mt], bf[nt], acc[mt][nt], 0, 0, 0);
      }
    }
  }
  // epilogue: D row=(q*4+r), col=t within each 16x16 tile
#pragma unroll
  for (int mt = 0; mt < 2; ++mt) {
    int om = m0 + mt * 16 + q * 4;
#pragma unroll
    for (int r = 0; r < 4; ++r) {
      float bias = bcw[om + r];
      short* orow = cb + ((size_t)b * CC + om + r) * HW + h * 64;
#pragma unroll
      for (int nt = 0; nt < 4; ++nt)
        orow[nt * 16 + t] = f2b(acc[mt][nt][r] + bias);
    }
  }
}

// ---------------- K6: InstanceNorm (biased var, eps=1e-5) + ReLU; bf16 in, f32 out
__global__ __launch_bounds__(256) void k_inorm(
    const short* __restrict__ cb, float* __restrict__ out)
{
  __shared__ float buf[4096];
  __shared__ float red[8];
  const int tid = threadIdx.x;
  const int ch = blockIdx.x;                 // b*256 + c
  const short* srcp = cb + (size_t)ch * HW;

  float s = 0.f, sq = 0.f;
#pragma unroll
  for (int u = 0; u < 2; ++u) {
    int sidx = u * 2048 + tid * 8;
    uint4 pk = *(const uint4*)(srcp + sidx);
    float f[8];
    f[0] = __uint_as_float(pk.x << 16); f[1] = __uint_as_float(pk.x & 0xffff0000u);
    f[2] = __uint_as_float(pk.y << 16); f[3] = __uint_as_float(pk.y & 0xffff0000u);
    f[4] = __uint_as_float(pk.z << 16); f[5] = __uint_as_float(pk.z & 0xffff0000u);
    f[6] = __uint_as_float(pk.w << 16); f[7] = __uint_as_float(pk.w & 0xffff0000u);
#pragma unroll
    for (int e = 0; e < 8; ++e) {
      buf[sidx + e] = f[e];
      s += f[e];
      sq += f[e] * f[e];
    }
  }
#pragma unroll
  for (int m = 32; m >= 1; m >>= 1) {
    s  += __shfl_xor(s, m, 64);
    sq += __shfl_xor(sq, m, 64);
  }
  if ((tid & 63) == 0) { red[tid >> 6] = s; red[4 + (tid >> 6)] = sq; }
  __syncthreads();
  if (tid == 0) {
    float S = red[0] + red[1] + red[2] + red[3];
    float Q = red[4] + red[5] + red[6] + red[7];
    float mean = S * (1.f / HW);
    float var = Q * (1.f / HW) - mean * mean;
    red[0] = mean;
    red[1] = rsqrtf(var + 1e-5f);
  }
  __syncthreads();
  const float mean = red[0], rs = red[1];
#pragma unroll
  for (int u = 0; u < 4; ++u) {
    int idx = u * 1024 + tid * 4;
    float4 v = *(const float4*)&buf[idx];
    float4 o4 = make_float4(fmaxf((v.x - mean) * rs, 0.f),
                            fmaxf((v.y - mean) * rs, 0.f),
                            fmaxf((v.z - mean) * rs, 0.f),
                            fmaxf((v.w - mean) * rs, 0.f));
    *(float4*)&out[(size_t)ch * HW + idx] = o4;
  }
}

extern "C" void kernel_launch(void* const* d_in, const int* in_sizes, int n_in,
                              void* d_out, int out_size, void* d_ws, size_t ws_size,
                              hipStream_t stream) {
  const float* src  = (const float*)d_in[0];
  const float* tgt  = (const float*)d_in[1];
  const float* prev = (const float*)d_in[2];
  const float* Wq = (const float*)d_in[3];  const float* bq = (const float*)d_in[4];
  const float* Wk = (const float*)d_in[5];  const float* bk = (const float*)d_in[6];
  const float* Wv = (const float*)d_in[7];  const float* bv = (const float*)d_in[8];
  const float* Wp = (const float*)d_in[9];  const float* bp = (const float*)d_in[10];
  const float* gamma = (const float*)d_in[11];
  const float* Wc = (const float*)d_in[12]; const float* bcw = (const float*)d_in[13];

  float* ws = (float*)d_ws;
  // f32 region (floats):
  float* qw   = ws;                 // [0, 2097152)
  float* kw   = ws + 2097152;       // [2097152, 4194304)
  float* vw   = ws + 4194304;       // [4194304, 6291456)
  float* rl   = ws + 6291456;       // [6291456, 6307840)
  float* ao   = ws + 6307840;       // [6307840, 8404992)
  float* yb   = ws;                 // alias qw+kw (dead after k_attnout)
  // bf16 regions (shorts), expressed as float offsets:
  short* Xn   = (short*)(ws + 4194304);   // 12.58M shorts over vw/rl/ao (dead after k_proj)
  short* cb   = (short*)(ws);             // 4.19M shorts over yb (dead after k_pack)
  short* Wb   = (short*)(ws + 10485760);  // 1.77M shorts
  // total ws footprint: 11,370,496 floats = 45.5 MB

  k_wb     <<<dim3(6912),      256, 0, stream>>>(Wc, Wb);
  k_qkv    <<<dim3(64, 3, BB), 256, 0, stream>>>(src, tgt, Wq, bq, Wk, bk, Wv, bv, qw, kw, vw);
  k_lsum   <<<dim3(64, BB),    256, 0, stream>>>(qw, kw, rl);
  k_attnout<<<dim3(64, BB),    256, 0, stream>>>(qw, kw, vw, rl, ao);
  k_proj   <<<dim3(64, 2, BB), 256, 0, stream>>>(ao, tgt, Wp, bp, gamma, yb);
  k_pack   <<<dim3(64, 12, BB), 256, 0, stream>>>(yb, prev, Xn);
  k_conv_mfma<<<dim3(64, 2, BB), 256, 0, stream>>>(Xn, Wb, bcw, cb);
  k_inorm  <<<dim3(1024),      256, 0, stream>>>(cb, (float*)d_out);
}

// Round 4
// 797.894 us; speedup vs baseline: 3.0405x; 1.8116x over previous
//
#include <hip/hip_runtime.h>
#include <hip/hip_bf16.h>

#define BB 4
#define CC 256
#define HW 4096
#define DD 128

typedef __attribute__((ext_vector_type(8))) short bf16x8;
typedef __attribute__((ext_vector_type(4))) float f32x4;

static __device__ __forceinline__ void ld4(float* dst, const float* src) {
  float4 t = *(const float4*)src;
  dst[0] = t.x; dst[1] = t.y; dst[2] = t.z; dst[3] = t.w;
}

// float -> bf16 (RNE) raw bits
static __device__ __forceinline__ short f2b(float f) {
  unsigned u = __float_as_uint(f);
  u += 0x7fffu + ((u >> 16) & 1u);
  return (short)(u >> 16);
}
static __device__ __forceinline__ unsigned pk2(float lo, float hi) {
  return (unsigned)(unsigned short)f2b(lo) | ((unsigned)(unsigned short)f2b(hi) << 16);
}

// ---------------- K1: q/k/v 1x1 conv. GEMM (128x256)@(256x4096) per (which,b)
__global__ __launch_bounds__(256) void k_qkv(
    const float* __restrict__ src, const float* __restrict__ tgt,
    const float* __restrict__ Wq, const float* __restrict__ bq,
    const float* __restrict__ Wk, const float* __restrict__ bk,
    const float* __restrict__ Wv, const float* __restrict__ bv,
    float* __restrict__ qw, float* __restrict__ kwp, float* __restrict__ vwp)
{
  __shared__ float Wt[32][132];
  __shared__ float Xs[32][68];
  const int tid = threadIdx.x;
  const int tx = tid & 15, ty = tid >> 4;
  const int p0 = blockIdx.x * 64;
  const int which = blockIdx.y;
  const int b = blockIdx.z;
  const float* X    = (which == 0) ? src : tgt;
  const float* Wm   = (which == 0) ? Wq : (which == 1) ? Wk : Wv;
  const float* bias = (which == 0) ? bq : (which == 1) ? bk : bv;
  float* out        = (which == 0) ? qw : (which == 1) ? kwp : vwp;

  float acc[8][4];
#pragma unroll
  for (int i = 0; i < 8; ++i)
#pragma unroll
    for (int j = 0; j < 4; ++j) acc[i][j] = 0.f;

  for (int kk = 0; kk < CC; kk += 32) {
    __syncthreads();
#pragma unroll
    for (int u = 0; u < 4; ++u) {
      int e = tid + 256 * u;
      int c4 = (e & 7) * 4, r = e >> 3;
      float w[4]; ld4(w, &Wm[r * CC + kk + c4]);
      Wt[c4 + 0][r] = w[0]; Wt[c4 + 1][r] = w[1];
      Wt[c4 + 2][r] = w[2]; Wt[c4 + 3][r] = w[3];
    }
#pragma unroll
    for (int u = 0; u < 2; ++u) {
      int e = tid + 256 * u;
      int p4 = (e & 15) * 4, c = e >> 4;
      *(float4*)&Xs[c][p4] = *(const float4*)&X[(b * CC + kk + c) * HW + p0 + p4];
    }
    __syncthreads();
#pragma unroll 4
    for (int c = 0; c < 32; ++c) {
      float wa[8], xb[4];
      ld4(wa, &Wt[c][ty * 8]); ld4(wa + 4, &Wt[c][ty * 8 + 4]);
      ld4(xb, &Xs[c][tx * 4]);
#pragma unroll
      for (int rr = 0; rr < 8; ++rr)
#pragma unroll
        for (int pp = 0; pp < 4; ++pp) acc[rr][pp] += wa[rr] * xb[pp];
    }
  }
#pragma unroll
  for (int rr = 0; rr < 8; ++rr) {
    int r = ty * 8 + rr;
    float bv_ = bias[r];
    float4 o4 = make_float4(acc[rr][0] + bv_, acc[rr][1] + bv_,
                            acc[rr][2] + bv_, acc[rr][3] + bv_);
    *(float4*)&out[(b * DD + r) * HW + p0 + tx * 4] = o4;
  }
}

// ---------------- K1b: transpose+cast q,k: (B,128,HW) f32 -> (B,HW,128) bf16
__global__ __launch_bounds__(256) void k_qkb(
    const float* __restrict__ qw, const float* __restrict__ kw,
    short* __restrict__ qb, short* __restrict__ kb)
{
  __shared__ float tile[64][65];
  const int tid = threadIdx.x;
  const int p0 = blockIdx.x * 64;
  const int ct = (blockIdx.y & 1) * 64;
  const int tens = blockIdx.y >> 1;
  const int b = blockIdx.z;
  const float* in = tens ? kw : qw;
  short* out = tens ? kb : qb;

  {
    int w = tid & 63, r = tid >> 6;
#pragma unroll
    for (int u = 0; u < 16; u += 4) {
      int cl = u + r;
      tile[cl][w] = in[((size_t)b * DD + ct + cl) * HW + p0 + w];
      tile[cl + 16][w] = in[((size_t)b * DD + ct + cl + 16) * HW + p0 + w];
      tile[cl + 32][w] = in[((size_t)b * DD + ct + cl + 32) * HW + p0 + w];
      tile[cl + 48][w] = in[((size_t)b * DD + ct + cl + 48) * HW + p0 + w];
    }
  }
  __syncthreads();
  {
    int p = tid >> 2, cq = (tid & 3) * 16;
    unsigned* dst = (unsigned*)(out + ((size_t)b * HW + p0 + p) * DD + ct + cq);
#pragma unroll
    for (int e = 0; e < 8; ++e)
      dst[e] = pk2(tile[cq + 2 * e][p], tile[cq + 2 * e + 1][p]);
  }
}

// ---------------- K2: pass1 MFMA: rl[j] = 1 / sum_i exp(s[i,j])
__global__ __launch_bounds__(256) void k_lsum2(
    const short* __restrict__ qb, const short* __restrict__ kb,
    float* __restrict__ rl)
{
  __shared__ float lred[4][64];
  const int tid = threadIdx.x;
  const int w = tid >> 6;
  const int lane = tid & 63;
  const int t = lane & 15, q = lane >> 4;
  const int j0 = blockIdx.x * 64;
  const int b = blockIdx.y;
  const short* qbb = qb + (size_t)b * HW * DD;
  const short* kbb = kb + (size_t)b * HW * DD;

  // preload Q fragments for this j-tile: B[k=c][n=j]
  bf16x8 Bq[4][4];
#pragma unroll
  for (int nt = 0; nt < 4; ++nt)
#pragma unroll
    for (int kk = 0; kk < 4; ++kk)
      Bq[nt][kk] = *(const bf16x8*)(qbb + (size_t)(j0 + nt * 16 + t) * DD + kk * 32 + q * 8);

  float racc[4] = {0.f, 0.f, 0.f, 0.f};
  const f32x4 zf = {0.f, 0.f, 0.f, 0.f};

  for (int i = w * 16; i < HW; i += 64) {
    bf16x8 Ak[4];
#pragma unroll
    for (int kk = 0; kk < 4; ++kk)
      Ak[kk] = *(const bf16x8*)(kbb + (size_t)(i + t) * DD + kk * 32 + q * 8);
#pragma unroll
    for (int nt = 0; nt < 4; ++nt) {
      f32x4 d = zf;
#pragma unroll
      for (int kk = 0; kk < 4; ++kk)
        d = __builtin_amdgcn_mfma_f32_16x16x32_bf16(Ak[kk], Bq[nt][kk], d, 0, 0, 0);
      racc[nt] += __expf(d[0]) + __expf(d[1]) + __expf(d[2]) + __expf(d[3]);
    }
  }
#pragma unroll
  for (int nt = 0; nt < 4; ++nt) {
    float r = racc[nt];
    r += __shfl_xor(r, 16);
    r += __shfl_xor(r, 32);
    if (q == 0) lred[w][nt * 16 + t] = r;
  }
  __syncthreads();
  if (tid < 64) {
    float sum = lred[0][tid] + lred[1][tid] + lred[2][tid] + lred[3][tid];
    rl[(size_t)b * HW + j0 + tid] = 1.f / sum;
  }
}

// ---------------- K2b: vs[c][j] = bf16( vw[c][j] * rl[j] )   (B,128,HW)
__global__ __launch_bounds__(256) void k_vs(
    const float* __restrict__ vw, const float* __restrict__ rl,
    short* __restrict__ vs)
{
  int id4 = (blockIdx.x * 256 + threadIdx.x) * 4;   // 2,097,152 elems total
  int j = id4 & (HW - 1);
  int b = id4 >> 19;                                 // / (128*4096)
  float4 v = *(const float4*)&vw[id4];
  const float* rlb = rl + (size_t)b * HW + j;
  unsigned u0 = pk2(v.x * rlb[0], v.y * rlb[1]);
  unsigned u1 = pk2(v.z * rlb[2], v.w * rlb[3]);
  *(uint2*)(vs + id4) = make_uint2(u0, u1);
}

// ---------------- K3: pass2 MFMA: ao[i, :] += exp(S_i,jrange) @ Vs
__global__ __launch_bounds__(256) void k_attn2(
    const short* __restrict__ qb, const short* __restrict__ kb,
    const short* __restrict__ vs, float* __restrict__ ao)
{
  __shared__ __align__(16) short P[4][32][72];
  const int tid = threadIdx.x;
  const int w = tid >> 6;
  const int lane = tid & 63;
  const int t = lane & 15, q = lane >> 4;
  const int b = blockIdx.z;
  const int i0 = blockIdx.x * 128 + w * 32;
  const int jbeg = blockIdx.y * 2048, jend = jbeg + 2048;
  const short* qbb = qb + (size_t)b * HW * DD;
  const short* kbb = kb + (size_t)b * HW * DD;
  const short* vsb = vs + (size_t)b * DD * HW;
  const f32x4 zf = {0.f, 0.f, 0.f, 0.f};

  // preload K^T fragments for wave's 32 i-rows: A[m=i][k=c]
  bf16x8 Ak[2][4];
#pragma unroll
  for (int mt = 0; mt < 2; ++mt)
#pragma unroll
    for (int kk = 0; kk < 4; ++kk)
      Ak[mt][kk] = *(const bf16x8*)(kbb + (size_t)(i0 + mt * 16 + t) * DD + kk * 32 + q * 8);

  f32x4 acc[2][8];
#pragma unroll
  for (int mt = 0; mt < 2; ++mt)
#pragma unroll
    for (int nt = 0; nt < 8; ++nt) acc[mt][nt] = zf;

  for (int j = jbeg; j < jend; j += 64) {
    // --- S chunk: 32 i x 64 j
    f32x4 sv[2][4];
#pragma unroll
    for (int mt = 0; mt < 2; ++mt)
#pragma unroll
      for (int nt = 0; nt < 4; ++nt) sv[mt][nt] = zf;
#pragma unroll
    for (int nt = 0; nt < 4; ++nt) {
#pragma unroll
      for (int kk = 0; kk < 4; ++kk) {
        bf16x8 bq = *(const bf16x8*)(qbb + (size_t)(j + nt * 16 + t) * DD + kk * 32 + q * 8);
        sv[0][nt] = __builtin_amdgcn_mfma_f32_16x16x32_bf16(Ak[0][kk], bq, sv[0][nt], 0, 0, 0);
        sv[1][nt] = __builtin_amdgcn_mfma_f32_16x16x32_bf16(Ak[1][kk], bq, sv[1][nt], 0, 0, 0);
      }
    }
    // --- exp -> P (bf16) in per-wave LDS tile, C/D layout -> [i][j]
#pragma unroll
    for (int mt = 0; mt < 2; ++mt)
#pragma unroll
      for (int nt = 0; nt < 4; ++nt)
#pragma unroll
        for (int r = 0; r < 4; ++r)
          P[w][mt * 16 + q * 4 + r][nt * 16 + t] = f2b(__expf(sv[mt][nt][r]));
    __syncthreads();
    // --- PV: A = P fragments, B = Vs fragments
    bf16x8 ap[2][2];
#pragma unroll
    for (int mt = 0; mt < 2; ++mt)
#pragma unroll
      for (int ks = 0; ks < 2; ++ks)
        ap[mt][ks] = *(const bf16x8*)&P[w][mt * 16 + t][ks * 32 + q * 8];
#pragma unroll
    for (int nt = 0; nt < 8; ++nt) {
#pragma unroll
      for (int ks = 0; ks < 2; ++ks) {
        bf16x8 bv = *(const bf16x8*)(vsb + (size_t)(nt * 16 + t) * HW + j + ks * 32 + q * 8);
        acc[0][nt] = __builtin_amdgcn_mfma_f32_16x16x32_bf16(ap[0][ks], bv, acc[0][nt], 0, 0, 0);
        acc[1][nt] = __builtin_amdgcn_mfma_f32_16x16x32_bf16(ap[1][ks], bv, acc[1][nt], 0, 0, 0);
      }
    }
    __syncthreads();
  }
  // epilogue: atomic accumulate partials into ao (B,128,HW)
  float* aob = ao + (size_t)b * DD * HW;
#pragma unroll
  for (int mt = 0; mt < 2; ++mt)
#pragma unroll
    for (int nt = 0; nt < 8; ++nt)
#pragma unroll
      for (int r = 0; r < 4; ++r)
        atomicAdd(&aob[(size_t)(nt * 16 + t) * HW + i0 + mt * 16 + q * 4 + r],
                  acc[mt][nt][r]);
}

// ---------------- K4: y = tgt + gamma*(Wp@ao + bp) -> Xn channels [0,256) (NHWC bf16)
__global__ __launch_bounds__(256) void k_proj(
    const float* __restrict__ ao, const float* __restrict__ tgt,
    const float* __restrict__ Wp, const float* __restrict__ bp,
    const float* __restrict__ gamma, short* __restrict__ Xn)
{
  __shared__ float Wt[32][132];
  __shared__ float Xs[32][68];
  __shared__ float T[64][133];
  const int tid = threadIdx.x;
  const int tx = tid & 15, ty = tid >> 4;
  const int p0 = blockIdx.x * 64;
  const int ro = blockIdx.y * 128;
  const int b = blockIdx.z;
  const float g0 = gamma[0];

  float acc[8][4];
#pragma unroll
  for (int i = 0; i < 8; ++i)
#pragma unroll
    for (int j = 0; j < 4; ++j) acc[i][j] = 0.f;

  for (int kk = 0; kk < DD; kk += 32) {
    __syncthreads();
#pragma unroll
    for (int u = 0; u < 4; ++u) {
      int e = tid + 256 * u;
      int c4 = (e & 7) * 4, r = e >> 3;
      float w[4]; ld4(w, &Wp[(ro + r) * DD + kk + c4]);
      Wt[c4 + 0][r] = w[0]; Wt[c4 + 1][r] = w[1];
      Wt[c4 + 2][r] = w[2]; Wt[c4 + 3][r] = w[3];
    }
#pragma unroll
    for (int u = 0; u < 2; ++u) {
      int e = tid + 256 * u;
      int p4 = (e & 15) * 4, c = e >> 4;
      *(float4*)&Xs[c][p4] = *(const float4*)&ao[(b * DD + kk + c) * HW + p0 + p4];
    }
    __syncthreads();
#pragma unroll 4
    for (int c = 0; c < 32; ++c) {
      float wa[8], xb[4];
      ld4(wa, &Wt[c][ty * 8]); ld4(wa + 4, &Wt[c][ty * 8 + 4]);
      ld4(xb, &Xs[c][tx * 4]);
#pragma unroll
      for (int rr = 0; rr < 8; ++rr)
#pragma unroll
        for (int pp = 0; pp < 4; ++pp) acc[rr][pp] += wa[rr] * xb[pp];
    }
  }
  // y into LDS transposed [pixel][ch]
#pragma unroll
  for (int rr = 0; rr < 8; ++rr) {
    int r = ro + ty * 8 + rr;
    int idx = (b * CC + r) * HW + p0 + tx * 4;
    float4 t4 = *(const float4*)&tgt[idx];
    float bpv = bp[r];
    T[tx * 4 + 0][ty * 8 + rr] = t4.x + g0 * (acc[rr][0] + bpv);
    T[tx * 4 + 1][ty * 8 + rr] = t4.y + g0 * (acc[rr][1] + bpv);
    T[tx * 4 + 2][ty * 8 + rr] = t4.z + g0 * (acc[rr][2] + bpv);
    T[tx * 4 + 3][ty * 8 + rr] = t4.w + g0 * (acc[rr][3] + bpv);
  }
  __syncthreads();
  {
    int p = tid >> 2, cq = (tid & 3) * 32;
    unsigned* dst = (unsigned*)(Xn + ((size_t)b * HW + p0 + p) * 768 + ro + cq);
#pragma unroll
    for (int e = 0; e < 16; ++e)
      dst[e] = pk2(T[p][cq + 2 * e], T[p][cq + 2 * e + 1]);
  }
}

// ---------------- K4b: upsample prev into Xn channels [256,768)
__global__ __launch_bounds__(256) void k_pack(
    const float* __restrict__ prev, short* __restrict__ Xn)
{
  __shared__ float tile[64][65];
  const int tid = threadIdx.x;
  const int h = blockIdx.x;
  const int ci0 = blockIdx.y * 64;
  const int b = blockIdx.z;

  {
    int w = tid & 63, r = tid >> 6;
    for (int cs = r; cs < 64; cs += 4)
      tile[cs][w] = prev[((size_t)b * 512 + ci0 + cs) * 1024 + (h >> 1) * 32 + (w >> 1)];
  }
  __syncthreads();
  {
    int ci = tid & 63, wq = tid >> 6;
    for (int ws2 = wq; ws2 < 64; ws2 += 4)
      Xn[(((size_t)b * 64 + h) * 64 + ws2) * 768 + 256 + ci0 + ci] = f2b(tile[ci][ws2]);
  }
}

// ---------------- K4c: weight repack Wc(256,768,3,3) f32 -> Wb(256,9,768) bf16
__global__ __launch_bounds__(256) void k_wb(
    const float* __restrict__ Wc, short* __restrict__ Wb)
{
  int i = blockIdx.x * 256 + threadIdx.x;
  int o = i / 6912;
  int rem = i - o * 6912;
  int khw = rem / 768;
  int ci = rem - khw * 768;
  Wb[i] = f2b(Wc[(size_t)o * 6912 + ci * 9 + khw]);
}

// ---------------- K5: 3x3 conv, implicit GEMM, bf16 MFMA -> cb (bf16)
__global__ __launch_bounds__(256) void k_conv_mfma(
    const short* __restrict__ Xn,   // (B,64,64,768) bf16
    const short* __restrict__ Wb,   // (256,9,768) bf16
    const float* __restrict__ bcw,
    short* __restrict__ cb)         // (B,256,4096) bf16
{
  const int tid = threadIdx.x;
  const int wv = tid >> 6;
  const int lane = tid & 63;
  const int t = lane & 15, q = lane >> 4;
  const int h = blockIdx.x;
  const int m0 = blockIdx.y * 128 + wv * 32;
  const int b = blockIdx.z;

  const f32x4 zf = {0.f, 0.f, 0.f, 0.f};
  const bf16x8 zb = {0, 0, 0, 0, 0, 0, 0, 0};
  f32x4 acc[2][4];
#pragma unroll
  for (int mt = 0; mt < 2; ++mt)
#pragma unroll
    for (int nt = 0; nt < 4; ++nt) acc[mt][nt] = zf;

  for (int ci0 = 0; ci0 < 768; ci0 += 32) {
    for (int kh = 0; kh < 3; ++kh) {
      const int hr = h + kh - 1;
      const bool vh = ((unsigned)hr < 64u);
      const short* xrow = Xn + (((size_t)b * 64 + hr) * 64) * 768 + ci0 + q * 8;
      const short* wrow = Wb + (size_t)(m0 + t) * 6912 + kh * 3 * 768 + ci0 + q * 8;
#pragma unroll
      for (int kw = 0; kw < 3; ++kw) {
        bf16x8 bf[4];
#pragma unroll
        for (int nt = 0; nt < 4; ++nt) {
          int col = nt * 16 + t + kw - 1;
          bf[nt] = (vh && (unsigned)col < 64u)
                       ? *(const bf16x8*)(xrow + (ptrdiff_t)col * 768)
                       : zb;
        }
        bf16x8 af[2];
        af[0] = *(const bf16x8*)(wrow + kw * 768);
        af[1] = *(const bf16x8*)(wrow + 16 * 6912 + kw * 768);
#pragma unroll
        for (int mt = 0; mt < 2; ++mt)
#pragma unroll
          for (int nt = 0; nt < 4; ++nt)
            acc[mt][nt] = __builtin_amdgcn_mfma_f32_16x16x32_bf16(
                af[mt], bf[nt], acc[mt][nt], 0, 0, 0);
      }
    }
  }
#pragma unroll
  for (int mt = 0; mt < 2; ++mt) {
    int om = m0 + mt * 16 + q * 4;
#pragma unroll
    for (int r = 0; r < 4; ++r) {
      float bias = bcw[om + r];
      short* orow = cb + ((size_t)b * CC + om + r) * HW + h * 64;
#pragma unroll
      for (int nt = 0; nt < 4; ++nt)
        orow[nt * 16 + t] = f2b(acc[mt][nt][r] + bias);
    }
  }
}

// ---------------- K6: InstanceNorm (biased var, eps=1e-5) + ReLU; bf16 in, f32 out
__global__ __launch_bounds__(256) void k_inorm(
    const short* __restrict__ cb, float* __restrict__ out)
{
  __shared__ float buf[4096];
  __shared__ float red[8];
  const int tid = threadIdx.x;
  const int ch = blockIdx.x;
  const short* srcp = cb + (size_t)ch * HW;

  float s = 0.f, sq = 0.f;
#pragma unroll
  for (int u = 0; u < 2; ++u) {
    int sidx = u * 2048 + tid * 8;
    uint4 pk = *(const uint4*)(srcp + sidx);
    float f[8];
    f[0] = __uint_as_float(pk.x << 16); f[1] = __uint_as_float(pk.x & 0xffff0000u);
    f[2] = __uint_as_float(pk.y << 16); f[3] = __uint_as_float(pk.y & 0xffff0000u);
    f[4] = __uint_as_float(pk.z << 16); f[5] = __uint_as_float(pk.z & 0xffff0000u);
    f[6] = __uint_as_float(pk.w << 16); f[7] = __uint_as_float(pk.w & 0xffff0000u);
#pragma unroll
    for (int e = 0; e < 8; ++e) {
      buf[sidx + e] = f[e];
      s += f[e];
      sq += f[e] * f[e];
    }
  }
#pragma unroll
  for (int m = 32; m >= 1; m >>= 1) {
    s  += __shfl_xor(s, m, 64);
    sq += __shfl_xor(sq, m, 64);
  }
  if ((tid & 63) == 0) { red[tid >> 6] = s; red[4 + (tid >> 6)] = sq; }
  __syncthreads();
  if (tid == 0) {
    float S = red[0] + red[1] + red[2] + red[3];
    float Q = red[4] + red[5] + red[6] + red[7];
    float mean = S * (1.f / HW);
    float var = Q * (1.f / HW) - mean * mean;
    red[0] = mean;
    red[1] = rsqrtf(var + 1e-5f);
  }
  __syncthreads();
  const float mean = red[0], rs = red[1];
#pragma unroll
  for (int u = 0; u < 4; ++u) {
    int idx = u * 1024 + tid * 4;
    float4 v = *(const float4*)&buf[idx];
    float4 o4 = make_float4(fmaxf((v.x - mean) * rs, 0.f),
                            fmaxf((v.y - mean) * rs, 0.f),
                            fmaxf((v.z - mean) * rs, 0.f),
                            fmaxf((v.w - mean) * rs, 0.f));
    *(float4*)&out[(size_t)ch * HW + idx] = o4;
  }
}

extern "C" void kernel_launch(void* const* d_in, const int* in_sizes, int n_in,
                              void* d_out, int out_size, void* d_ws, size_t ws_size,
                              hipStream_t stream) {
  const float* src  = (const float*)d_in[0];
  const float* tgt  = (const float*)d_in[1];
  const float* prev = (const float*)d_in[2];
  const float* Wq = (const float*)d_in[3];  const float* bq = (const float*)d_in[4];
  const float* Wk = (const float*)d_in[5];  const float* bk = (const float*)d_in[6];
  const float* Wv = (const float*)d_in[7];  const float* bv = (const float*)d_in[8];
  const float* Wp = (const float*)d_in[9];  const float* bp = (const float*)d_in[10];
  const float* gamma = (const float*)d_in[11];
  const float* Wc = (const float*)d_in[12]; const float* bcw = (const float*)d_in[13];

  float* ws = (float*)d_ws;
  // float-unit offsets; lifetimes annotated (see session journal):
  float* qw = ws;                         // [0, 2097152)        dead after k_qkb
  float* kw = ws + 2097152;               // [2097152, 4194304)  dead after k_qkb
  float* vw = ws + 4194304;               // [4194304, 6291456)  dead after k_vs
  float* rl = ws + 6291456;               // [6291456, 6307840)  dead after k_vs
  short* qb = (short*)(ws + 6307840);     // [6307840, 7356416)  dead after k_attn2
  short* kb = (short*)(ws + 7356416);     // [7356416, 8404992)  dead after k_attn2
  short* vs = (short*)(ws + 8404992);     // [8404992, 9453568)  dead after k_attn2
  float* ao = ws;                         // [0, 2097152)  over qw; zeroed below
  short* Xn = (short*)(ws + 2097152);     // [2097152, 8388608)  over kw/vw/rl/qb/kb
  short* cb = (short*)(ws);               // [0, 2097152)  over ao (dead after k_proj)
  short* Wb = (short*)(ws + 8404992);     // [8404992, 9289728)  over vs
  // high-water: 9,453,568 floats = 37.8 MB

  k_qkv  <<<dim3(64, 3, BB), 256, 0, stream>>>(src, tgt, Wq, bq, Wk, bk, Wv, bv, qw, kw, vw);
  k_qkb  <<<dim3(64, 4, BB), 256, 0, stream>>>(qw, kw, qb, kb);
  k_lsum2<<<dim3(64, BB),    256, 0, stream>>>(qb, kb, rl);
  k_vs   <<<dim3(2048),      256, 0, stream>>>(vw, rl, vs);
  hipMemsetAsync(ao, 0, (size_t)2097152 * 4, stream);
  k_attn2<<<dim3(32, 2, BB), 256, 0, stream>>>(qb, kb, vs, ao);
  k_proj <<<dim3(64, 2, BB), 256, 0, stream>>>(ao, tgt, Wp, bp, gamma, Xn);
  k_pack <<<dim3(64, 8, BB), 256, 0, stream>>>(prev, Xn);
  k_wb   <<<dim3(6912),      256, 0, stream>>>(Wc, Wb);
  k_conv_mfma<<<dim3(64, 2, BB), 256, 0, stream>>>(Xn, Wb, bcw, cb);
  k_inorm<<<dim3(1024),      256, 0, stream>>>(cb, (float*)d_out);
}